// Round 7
// baseline (553.532 us; speedup 1.0000x reference)
//
#include <hip/hip_runtime.h>

#define NNODES 20000
#define NEDGES 320000
#define DIM 256
#define DIM2 512
#define MPAD 20096          // 157 * 128
#define BN_EPS 1e-5f
#define NDTOT (NNODES * DIM)

typedef __attribute__((ext_vector_type(8))) short bf16x8;
typedef __attribute__((ext_vector_type(4))) float f32x4;

typedef __attribute__((address_space(1))) const unsigned char gconst_byte;
typedef __attribute__((address_space(3))) unsigned char lds_byte;

__device__ inline ushort f2bf(float f) {
    unsigned u = __float_as_uint(f);
    u += 0x7FFF + ((u >> 16) & 1);   // round-to-nearest-even
    return (ushort)(u >> 16);
}
__device__ inline float bf2f(ushort u) {
    return __uint_as_float(((unsigned)u) << 16);
}

// ---------------------------------------------------------------------------
// CSR build
__global__ void hist_kernel(const int* __restrict__ ei, int* __restrict__ cnt) {
    int e = blockIdx.x * blockDim.x + threadIdx.x;
    if (e < NEDGES) atomicAdd(&cnt[ei[NEDGES + e]], 1);
}

__global__ __launch_bounds__(256) void scan_kernel(const int* __restrict__ cnt,
                                                   int* __restrict__ off,
                                                   int* __restrict__ cur,
                                                   float* __restrict__ klP) {
    int t = threadIdx.x;
    const int CH = (NNODES + 255) / 256;
    int b0 = t * CH, b1 = min(b0 + CH, NNODES);
    int s = 0;
    for (int i = b0; i < b1; ++i) s += cnt[i];
    __shared__ int sums[256];
    sums[t] = s;
    __syncthreads();
    if (t == 0) {
        int acc = 0;
        for (int i = 0; i < 256; ++i) { int tmp = sums[i]; sums[i] = acc; acc += tmp; }
        off[NNODES] = acc;
        klP[0] = 0.f;                       // zero KL accumulator
    }
    __syncthreads();
    int run = sums[t];
    for (int i = b0; i < b1; ++i) {
        off[i] = run;
        cur[i] = run;
        run += cnt[i];
    }
}

__global__ void scatter_kernel(const int* __restrict__ ei, int* __restrict__ cur,
                               int* __restrict__ perm_e, int* __restrict__ perm_s) {
    int e = blockIdx.x * blockDim.x + threadIdx.x;
    if (e >= NEDGES) return;
    int d = ei[NEDGES + e];
    int pos = atomicAdd(&cur[d], 1);
    perm_e[pos] = e;
    perm_s[pos] = ei[e];
}

// ---------------------------------------------------------------------------
// One wave per node: A16[n] = bf16( X[n] + sum_{e->n} relu(X[src]+EA[e]) ).
// 1-deep software-pipelined gather (prefetch next edge's rows).
template<bool XF32, bool EAPERM, bool WEA>
__global__ __launch_bounds__(256) void agg_kernel(
        const float* __restrict__ Xf, const ushort* __restrict__ Xh,
        const float* __restrict__ EAf, const ushort* __restrict__ EAh,
        ushort* __restrict__ EAout,
        const int* __restrict__ off, const int* __restrict__ perm_e,
        const int* __restrict__ perm_s, ushort* __restrict__ A16) {
    int wid = (blockIdx.x * blockDim.x + threadIdx.x) >> 6;
    if (wid >= NNODES) return;
    int l = threadIdx.x & 63;
    int s0 = off[wid], s1 = off[wid + 1];

    auto loadX = [&](int s) -> float4 {
        if (XF32) return *(const float4*)(Xf + (size_t)s * DIM + l * 4);
        ushort4 v = *(const ushort4*)(Xh + (size_t)s * DIM + l * 4);
        return make_float4(bf2f(v.x), bf2f(v.y), bf2f(v.z), bf2f(v.w));
    };
    auto loadE = [&](int i) -> float4 {
        if (EAPERM) {
            ushort4 v = *(const ushort4*)(EAh + (size_t)i * DIM + l * 4);
            return make_float4(bf2f(v.x), bf2f(v.y), bf2f(v.z), bf2f(v.w));
        }
        int e = perm_e[i];
        return *(const float4*)(EAf + (size_t)e * DIM + l * 4);
    };

    float4 acc = loadX(wid);
    if (!XF32) { /* acc from bf16 already */ }

    int i = s0;
    float4 xc, ec;
    if (i < s1) { xc = loadX(perm_s[i]); ec = loadE(i); }
    while (i < s1) {
        float4 xr = xc, er = ec;
        int inext = i + 1;
        if (inext < s1) { xc = loadX(perm_s[inext]); ec = loadE(inext); }
        if (WEA) {
            ushort4 o;
            o.x = f2bf(er.x); o.y = f2bf(er.y); o.z = f2bf(er.z); o.w = f2bf(er.w);
            *(ushort4*)(EAout + (size_t)i * DIM + l * 4) = o;   // CSR slot order
        }
        acc.x += fmaxf(xr.x + er.x, 0.f);
        acc.y += fmaxf(xr.y + er.y, 0.f);
        acc.z += fmaxf(xr.z + er.z, 0.f);
        acc.w += fmaxf(xr.w + er.w, 0.f);
        i = inext;
    }
    ushort4 o;
    o.x = f2bf(acc.x); o.y = f2bf(acc.y); o.z = f2bf(acc.z); o.w = f2bf(acc.w);
    *(ushort4*)(A16 + (size_t)wid * DIM + l * 4) = o;
}

// ---------------------------------------------------------------------------
// Weight convert+transpose via LDS 64x64 tiles (coalesced read AND write).
// out[Nc][K] bf16 = in[K][Nc] fp32. All 8 weights; 32 tiles each.
struct WPtrs {
    const float* w[8];
    ushort* o[8];
    int K[8];
    int Nc[8];
};
__global__ __launch_bounds__(256) void wconv_kernel(WPtrs p) {
    __shared__ float T[64][65];
    int w = blockIdx.x >> 5;                 // 8 weights x 32 tiles
    int tile = blockIdx.x & 31;
    int K = p.K[w], Nc = p.Nc[w];
    int tilesPerRow = Nc >> 6;               // tiles along Nc
    int tk = (tile / tilesPerRow) << 6;      // K origin
    int tc = (tile % tilesPerRow) << 6;      // Nc origin
    int tx = threadIdx.x & 63, ty = threadIdx.x >> 6;   // 64x4
    const float* in = p.w[w];
    #pragma unroll
    for (int r = 0; r < 16; ++r) {
        int kk = ty + r * 4;
        T[kk][tx] = in[(size_t)(tk + kk) * Nc + tc + tx];
    }
    __syncthreads();
    ushort* outp = p.o[w];
    #pragma unroll
    for (int r = 0; r < 16; ++r) {
        int cc = ty + r * 4;                 // output row = Nc index
        outp[(size_t)(tc + cc) * K + tk + tx] = f2bf(T[tx][cc]);
    }
}

// ---------------------------------------------------------------------------
// BN-fold for layers 2/3 (no ReLU): W2f[l][n][k] = bf16(sc[k]*W2T[n][k]),
// b2f[l][n] = b2[n] + sum_k (be[k]-mu[k]*sc[k])*W2T[n][k].
__global__ __launch_bounds__(64) void wfold_kernel(
        const ushort* __restrict__ WT2_2, const ushort* __restrict__ WT2_3,
        const float* __restrict__ stats,
        const float* __restrict__ g2, const float* __restrict__ be2,
        const float* __restrict__ g3, const float* __restrict__ be3,
        const float* __restrict__ b2_2, const float* __restrict__ b2_3,
        ushort* __restrict__ W2f, float* __restrict__ b2f) {
    const int l = blockIdx.x >> 8;          // layer sel (0->conv2, 1->conv3)
    const int n = blockIdx.x & 255;
    const int lane = threadIdx.x;
    const float invN = 1.0f / (float)NNODES;
    const ushort* WT = l ? WT2_3 : WT2_2;
    const float* gp = l ? g3 : g2;
    const float* bp = l ? be3 : be2;
    float part = 0.f;
    #pragma unroll
    for (int j = 0; j < 8; ++j) {
        int k = j * 64 + lane;
        int c = l * DIM2 + k;
        float mu = stats[c] * invN;
        float var = stats[1024 + c] * invN - mu * mu;
        float sc = gp[k] * rsqrtf(var + BN_EPS);
        float sh = bp[k] - mu * sc;
        float wv = bf2f(WT[(size_t)n * DIM2 + k]);
        W2f[(size_t)l * 131072 + (size_t)n * DIM2 + k] = f2bf(sc * wv);
        part += sh * wv;
    }
    #pragma unroll
    for (int o = 32; o > 0; o >>= 1) part += __shfl_down(part, o);
    if (lane == 0) b2f[l * 256 + n] = (l ? b2_3[n] : b2_2[n]) + part;
}

// ---------------------------------------------------------------------------
// MFMA GEMM: out[gr][gc] = sum_k A16[gr][k]*WT[gc][k] + bias[gc]
// Block 128 x BCOLS, BK=64, 4 waves (2x2); wave tile 64 x (BCOLS/2).
// Staging: global_load_lds width=16, both-sides XOR swizzle (rule #21).
template<int K, int BCOLS, bool OUT_BF16, bool STATS, bool FINAL>
__global__ __launch_bounds__(256) void mfma_gemm(
        const ushort* __restrict__ A16, int lda,
        const ushort* __restrict__ WT,
        const float* __restrict__ bias, const float* __restrict__ bias2,
        float* __restrict__ Cf, ushort* __restrict__ C16, int ldc,
        float* __restrict__ stats, int Nc, int Mlimit,
        const float* __restrict__ meanP, const float* __restrict__ noiseP,
        float* __restrict__ zP, float* __restrict__ klP) {
    constexpr int NREP = BCOLS / 32;         // b-fragments per wave
    __shared__ ushort As[128 * 64];
    __shared__ ushort Bs[BCOLS * 64];
    const int tid = threadIdx.x;
    const int lane = tid & 63;
    const int wv = tid >> 6, wr = wv >> 1, wc = wv & 1;
    const int l15 = lane & 15, lhi = lane >> 4;
    const int r0 = blockIdx.y * 128, c0 = blockIdx.x * BCOLS;

    const int srow = lane >> 3;                       // 0..7
    const int scol = ((lane & 7) ^ srow) * 8;         // inverse-swizzled source col
    const int smask = (l15 & 7) << 4;                 // read-side swizzle mask

    f32x4 acc[4][NREP] = {};

    for (int k0 = 0; k0 < K; k0 += 64) {
        #pragma unroll
        for (int j = 0; j < 4; ++j) {
            const int jp = j * 4 + wv;
            const ushort* ga = A16 + (size_t)(r0 + jp * 8 + srow) * lda + k0 + scol;
            __builtin_amdgcn_global_load_lds(
                (gconst_byte*)ga, (lds_byte*)((char*)As + jp * 1024), 16, 0, 0);
        }
        #pragma unroll
        for (int j = 0; j < BCOLS / 32; ++j) {
            const int jp = j * 4 + wv;
            const ushort* gb = WT + (size_t)(c0 + jp * 8 + srow) * K + k0 + scol;
            __builtin_amdgcn_global_load_lds(
                (gconst_byte*)gb, (lds_byte*)((char*)Bs + jp * 1024), 16, 0, 0);
        }
        __syncthreads();
        #pragma unroll
        for (int kk = 0; kk < 2; ++kk) {
            bf16x8 a[4], b[NREP];
            #pragma unroll
            for (int m = 0; m < 4; ++m)
                a[m] = *(const bf16x8*)((const char*)As +
                        (wr * 64 + m * 16 + l15) * 128 + ((kk * 64 + lhi * 16) ^ smask));
            #pragma unroll
            for (int n = 0; n < NREP; ++n)
                b[n] = *(const bf16x8*)((const char*)Bs +
                        (wc * (BCOLS / 2) + n * 16 + l15) * 128 + ((kk * 64 + lhi * 16) ^ smask));
            #pragma unroll
            for (int m = 0; m < 4; ++m)
                #pragma unroll
                for (int n = 0; n < NREP; ++n)
                    acc[m][n] = __builtin_amdgcn_mfma_f32_16x16x32_bf16(
                        a[m], b[n], acc[m][n], 0, 0, 0);
        }
        __syncthreads();
    }

    float bv[NREP];
    #pragma unroll
    for (int n = 0; n < NREP; ++n) {
        int gc = c0 + wc * (BCOLS / 2) + n * 16 + l15;
        bv[n] = (gc < DIM2) ? bias[gc] : bias2[gc - DIM2];
    }
    float sm[NREP], sq[NREP];
    #pragma unroll
    for (int n = 0; n < NREP; ++n) { sm[n] = 0.f; sq[n] = 0.f; }
    float kl = 0.f;
    #pragma unroll
    for (int m = 0; m < 4; ++m) {
        #pragma unroll
        for (int q = 0; q < 4; ++q) {
            int gr = r0 + wr * 64 + m * 16 + lhi * 4 + q;
            if (gr >= Mlimit) continue;
            #pragma unroll
            for (int n = 0; n < NREP; ++n) {
                int gc = c0 + wc * (BCOLS / 2) + n * 16 + l15;
                float v = acc[m][n][q] + bv[n];
                if (OUT_BF16) C16[(size_t)gr * ldc + gc] = f2bf(v);
                else          Cf[(size_t)gr * ldc + gc] = v;
                if (STATS) { sm[n] += v; sq[n] += v * v; }
                if (FINAL) {
                    size_t idx = (size_t)gr * DIM + gc;
                    float mean = meanP[idx];
                    float nz = noiseP[idx];
                    float e = expf(v);
                    zP[idx] = nz * e + mean;
                    kl += 1.f + 2.f * v - mean * mean - e * e;
                }
            }
        }
    }
    if (STATS) {
        #pragma unroll
        for (int n = 0; n < NREP; ++n) {
            float sv = sm[n], qv = sq[n];
            sv += __shfl_xor(sv, 16); sv += __shfl_xor(sv, 32);
            qv += __shfl_xor(qv, 16); qv += __shfl_xor(qv, 32);
            if (lane < 16) {
                int gc = c0 + wc * (BCOLS / 2) + n * 16 + l15;
                atomicAdd(&stats[gc], sv);
                atomicAdd(&stats[Nc + gc], qv);
            }
        }
    }
    if (FINAL) {
        #pragma unroll
        for (int o = 32; o > 0; o >>= 1) kl += __shfl_down(kl, o);
        if (lane == 0) {
            const float scale = 0.5f / ((float)NNODES * (float)NNODES);
            atomicAdd(klP, kl * scale);
        }
    }
}

// ---------------------------------------------------------------------------
// BN apply in-place on bf16 [NNODES, NCOLS] (layers 0/1, ReLU).
template<int NCOLS>
__global__ __launch_bounds__(256) void bn_apply_kernel(
        ushort* __restrict__ H16, const float* __restrict__ stats,
        const float* __restrict__ g0, const float* __restrict__ be0) {
    const float invN = 1.0f / (float)NNODES;
    const int n4 = NNODES * NCOLS / 4;
    for (int i = blockIdx.x * blockDim.x + threadIdx.x; i < n4;
         i += gridDim.x * blockDim.x) {
        int cbase = (i * 4) & (NCOLS - 1);
        ushort4 u = ((const ushort4*)H16)[i];
        float vv[4] = {bf2f(u.x), bf2f(u.y), bf2f(u.z), bf2f(u.w)};
        #pragma unroll
        for (int k = 0; k < 4; ++k) {
            int c = cbase + k;
            float mu = stats[c] * invN;
            float var = stats[NCOLS + c] * invN - mu * mu;
            float x = (vv[k] - mu) * rsqrtf(var + BN_EPS) * g0[c] + be0[c];
            vv[k] = fmaxf(x, 0.f);
        }
        ushort4 o;
        o.x = f2bf(vv[0]); o.y = f2bf(vv[1]); o.z = f2bf(vv[2]); o.w = f2bf(vv[3]);
        ((ushort4*)H16)[i] = o;
    }
}

// ---------------------------------------------------------------------------
extern "C" void kernel_launch(void* const* d_in, const int* in_sizes, int n_in,
                              void* d_out, int out_size, void* d_ws, size_t ws_size,
                              hipStream_t stream) {
    const float* x     = (const float*)d_in[0];
    const int*   ei    = (const int*)d_in[1];
    const float* ea    = (const float*)d_in[2];
    const float* noise = (const float*)d_in[3];
    const float *W1[4], *b1[4], *g[4], *be[4], *W2[4], *b2[4];
    for (int i = 0; i < 4; ++i) {
        W1[i] = (const float*)d_in[4 + 6 * i];
        b1[i] = (const float*)d_in[5 + 6 * i];
        g[i]  = (const float*)d_in[6 + 6 * i];
        be[i] = (const float*)d_in[7 + 6 * i];
        W2[i] = (const float*)d_in[8 + 6 * i];
        b2[i] = (const float*)d_in[9 + 6 * i];
    }
    float* out = (float*)d_out;
    float* klP = out + 3 * NDTOT;

    // --- workspace carve
    char* p = (char*)d_ws;
    auto carve = [&](size_t bytes) {
        char* r = p;
        p += (bytes + 255) & ~(size_t)255;
        return r;
    };
    ushort* Braw16 = (ushort*)carve((size_t)MPAD * 1024 * 2);   // GEMM1 out (<=1024 cols)
    ushort* H16    = (ushort*)carve((size_t)MPAD * DIM * 2);    // hidden bf16
    ushort* A16    = (ushort*)carve((size_t)MPAD * DIM * 2);    // agg out bf16
    ushort* WT16   = (ushort*)carve((size_t)8 * 131072 * 2);    // 8 transposed weights
    ushort* W2f    = (ushort*)carve((size_t)2 * 131072 * 2);    // folded L23 weights
    float*  b2f    = (float*)carve(512 * 4);                    // folded L23 biases
    float*  stats  = (float*)carve(4096 * 4 + NNODES * 4);      // stats + cnt (one memset)
    int*    cnt    = (int*)(stats + 4096);
    int*    off    = (int*)carve((NNODES + 8) * 4);
    int*    cur    = (int*)carve(NNODES * 4);
    int*    perm_e = (int*)carve(NEDGES * 4);
    int*    perm_s = (int*)carve(NEDGES * 4);
    size_t baseBytes = (size_t)(p - (char*)d_ws);
    ushort* ea16 = (ushort*)p;
    const bool useEa16 = (baseBytes + (size_t)NEDGES * DIM * 2) <= ws_size;

    const int edgeGrid = (NEDGES + 255) / 256;
    const int aggGrid = (NNODES * 64) / 256;

    // --- weight convert + transpose (once). o[2],o[3] adjacent -> merged L23 W1.
    WPtrs wp;
    for (int i = 0; i < 4; ++i) {
        wp.w[i] = W1[i];     wp.o[i] = WT16 + (size_t)i * 131072;
        wp.K[i] = DIM;       wp.Nc[i] = DIM2;
        wp.w[4 + i] = W2[i]; wp.o[4 + i] = WT16 + (size_t)(4 + i) * 131072;
        wp.K[4 + i] = DIM2;  wp.Nc[4 + i] = DIM;
    }
    hipLaunchKernelGGL(wconv_kernel, dim3(8 * 32), dim3(256), 0, stream, wp);

    // --- zero stats + cnt in one fill; build CSR (scan also zeroes KL)
    hipMemsetAsync(stats, 0, 4096 * 4 + NNODES * 4, stream);
    hipLaunchKernelGGL(hist_kernel, dim3(edgeGrid), dim3(256), 0, stream, ei, cnt);
    hipLaunchKernelGGL(scan_kernel, dim3(1), dim3(256), 0, stream, cnt, off, cur, klP);
    hipLaunchKernelGGL(scatter_kernel, dim3(edgeGrid), dim3(256), 0, stream,
                       ei, cur, perm_e, perm_s);

    dim3 blk(256);
    dim3 gemm1Grid(DIM2 / 128, MPAD / 128);     // (4,157) 628 blocks
    dim3 gemm1WGrid(1024 / 128, MPAD / 128);    // (8,157) merged L23
    dim3 gemm2Grid(DIM / 64, MPAD / 128);       // (4,157) 628 blocks, 64-col tiles
    const float* nf = nullptr;
    float* nfm = nullptr;

    // ---------------- layer 0 ----------------
    if (useEa16)
        hipLaunchKernelGGL((agg_kernel<true, false, true>), dim3(aggGrid), blk, 0, stream,
                           x, (const ushort*)nullptr, ea, (const ushort*)nullptr, ea16,
                           off, perm_e, perm_s, A16);
    else
        hipLaunchKernelGGL((agg_kernel<true, false, false>), dim3(aggGrid), blk, 0, stream,
                           x, (const ushort*)nullptr, ea, (const ushort*)nullptr, (ushort*)nullptr,
                           off, perm_e, perm_s, A16);
    hipLaunchKernelGGL((mfma_gemm<DIM, 128, true, true, false>), gemm1Grid, blk, 0, stream,
                       A16, DIM, WT16, b1[0], b1[0],
                       nfm, Braw16, DIM2, stats, DIM2, NNODES, nf, nf, nfm, nfm);
    hipLaunchKernelGGL((bn_apply_kernel<DIM2>), dim3(2048), blk, 0, stream,
                       Braw16, stats, g[0], be[0]);
    hipLaunchKernelGGL((mfma_gemm<DIM2, 64, true, false, false>), gemm2Grid, blk, 0, stream,
                       Braw16, DIM2, WT16 + 4 * 131072, b2[0], b2[0],
                       nfm, H16, DIM, nfm, DIM, NNODES, nf, nf, nfm, nfm);

    // ---------------- layer 1 ----------------
    if (useEa16)
        hipLaunchKernelGGL((agg_kernel<false, true, false>), dim3(aggGrid), blk, 0, stream,
                           (const float*)nullptr, H16, (const float*)nullptr, ea16, (ushort*)nullptr,
                           off, perm_e, perm_s, A16);
    else
        hipLaunchKernelGGL((agg_kernel<false, false, false>), dim3(aggGrid), blk, 0, stream,
                           (const float*)nullptr, H16, ea, (const ushort*)nullptr, (ushort*)nullptr,
                           off, perm_e, perm_s, A16);
    hipLaunchKernelGGL((mfma_gemm<DIM, 128, true, true, false>), gemm1Grid, blk, 0, stream,
                       A16, DIM, WT16 + 1 * 131072, b1[1], b1[1],
                       nfm, Braw16, DIM2, stats + 1024, DIM2, NNODES, nf, nf, nfm, nfm);
    hipLaunchKernelGGL((bn_apply_kernel<DIM2>), dim3(2048), blk, 0, stream,
                       Braw16, stats + 1024, g[1], be[1]);
    hipLaunchKernelGGL((mfma_gemm<DIM2, 64, true, false, false>), gemm2Grid, blk, 0, stream,
                       Braw16, DIM2, WT16 + 5 * 131072, b2[1], b2[1],
                       nfm, H16, DIM, nfm, DIM, NNODES, nf, nf, nfm, nfm);

    // ---------------- layers 2+3 (merged GEMM1; BN folded into GEMM2) --------
    if (useEa16)
        hipLaunchKernelGGL((agg_kernel<false, true, false>), dim3(aggGrid), blk, 0, stream,
                           (const float*)nullptr, H16, (const float*)nullptr, ea16, (ushort*)nullptr,
                           off, perm_e, perm_s, A16);
    else
        hipLaunchKernelGGL((agg_kernel<false, false, false>), dim3(aggGrid), blk, 0, stream,
                           (const float*)nullptr, H16, ea, (const ushort*)nullptr, (ushort*)nullptr,
                           off, perm_e, perm_s, A16);
    hipLaunchKernelGGL((mfma_gemm<DIM, 128, true, true, false>), gemm1WGrid, blk, 0, stream,
                       A16, DIM, WT16 + 2 * 131072, b1[2], b1[3],
                       nfm, Braw16, 1024, stats + 2048, 1024, NNODES, nf, nf, nfm, nfm);
    hipLaunchKernelGGL(wfold_kernel, dim3(512), dim3(64), 0, stream,
                       WT16 + 6 * 131072, WT16 + 7 * 131072, stats + 2048,
                       g[2], be[2], g[3], be[3], b2[2], b2[3], W2f, b2f);
    // mean = Braw16[:,0:512] @ W2f_0 + b2f_0
    hipLaunchKernelGGL((mfma_gemm<DIM2, 64, false, false, false>), gemm2Grid, blk, 0, stream,
                       Braw16, 1024, W2f, b2f, b2f,
                       out + NDTOT, (ushort*)nullptr, DIM, nfm, DIM, NNODES, nf, nf, nfm, nfm);
    // logstd = Braw16[:,512:1024] @ W2f_1 + b2f_1 ; fused z + KL
    hipLaunchKernelGGL((mfma_gemm<DIM2, 64, false, false, true>), gemm2Grid, blk, 0, stream,
                       Braw16 + 512, 1024, W2f + 131072, b2f + 256, b2f + 256,
                       out + 2 * NDTOT, (ushort*)nullptr, DIM, nfm, DIM, NNODES,
                       out + NDTOT, noise, out, klP);
}

// Round 8
// 513.993 us; speedup vs baseline: 1.0769x; 1.0769x over previous
//
#include <hip/hip_runtime.h>

#define NNODES 20000
#define NEDGES 320000
#define DIM 256
#define DIM2 512
#define MPAD 20096          // 157 * 128
#define BN_EPS 1e-5f
#define NDTOT (NNODES * DIM)

typedef __attribute__((ext_vector_type(8))) short bf16x8;
typedef __attribute__((ext_vector_type(4))) float f32x4;

typedef __attribute__((address_space(1))) const unsigned char gconst_byte;
typedef __attribute__((address_space(3))) unsigned char lds_byte;

__device__ inline ushort f2bf(float f) {
    unsigned u = __float_as_uint(f);
    u += 0x7FFF + ((u >> 16) & 1);   // round-to-nearest-even
    return (ushort)(u >> 16);
}
__device__ inline float bf2f(ushort u) {
    return __uint_as_float(((unsigned)u) << 16);
}

// ---------------------------------------------------------------------------
// CSR build
__global__ void hist_kernel(const int* __restrict__ ei, int* __restrict__ cnt) {
    int e = blockIdx.x * blockDim.x + threadIdx.x;
    if (e < NEDGES) atomicAdd(&cnt[ei[NEDGES + e]], 1);
}

__global__ __launch_bounds__(256) void scan_kernel(const int* __restrict__ cnt,
                                                   int* __restrict__ off,
                                                   int* __restrict__ cur,
                                                   float* __restrict__ klP) {
    int t = threadIdx.x;
    const int CH = (NNODES + 255) / 256;
    int b0 = t * CH, b1 = min(b0 + CH, NNODES);
    int s = 0;
    for (int i = b0; i < b1; ++i) s += cnt[i];
    __shared__ int sums[256];
    sums[t] = s;
    __syncthreads();
    if (t == 0) {
        int acc = 0;
        for (int i = 0; i < 256; ++i) { int tmp = sums[i]; sums[i] = acc; acc += tmp; }
        off[NNODES] = acc;
        klP[0] = 0.f;                       // zero KL accumulator
    }
    __syncthreads();
    int run = sums[t];
    for (int i = b0; i < b1; ++i) {
        off[i] = run;
        cur[i] = run;
        run += cnt[i];
    }
}

__global__ void scatter_kernel(const int* __restrict__ ei, int* __restrict__ cur,
                               int* __restrict__ perm_e, int* __restrict__ perm_s) {
    int e = blockIdx.x * blockDim.x + threadIdx.x;
    if (e >= NEDGES) return;
    int d = ei[NEDGES + e];
    int pos = atomicAdd(&cur[d], 1);
    perm_e[pos] = e;
    perm_s[pos] = ei[e];
}

// ---------------------------------------------------------------------------
// One wave per node: A16[n] = bf16( X[n] + sum_{e->n} relu(X[src]+EA[e]) ).
// XF32: X fp32 (else bf16). EAPERM: EA bf16, CSR-slot-ordered (index i).
// WEA: write bf16 CSR-ordered copy of EA rows (pass 1).
template<bool XF32, bool EAPERM, bool WEA>
__global__ __launch_bounds__(256) void agg_kernel(
        const float* __restrict__ Xf, const ushort* __restrict__ Xh,
        const float* __restrict__ EAf, const ushort* __restrict__ EAh,
        ushort* __restrict__ EAout,
        const int* __restrict__ off, const int* __restrict__ perm_e,
        const int* __restrict__ perm_s, ushort* __restrict__ A16) {
    int wid = (blockIdx.x * blockDim.x + threadIdx.x) >> 6;
    if (wid >= NNODES) return;
    int l = threadIdx.x & 63;
    int s0 = off[wid], s1 = off[wid + 1];
    float4 acc;
    if (XF32) {
        acc = *(const float4*)(Xf + (size_t)wid * DIM + l * 4);
    } else {
        ushort4 v = *(const ushort4*)(Xh + (size_t)wid * DIM + l * 4);
        acc = make_float4(bf2f(v.x), bf2f(v.y), bf2f(v.z), bf2f(v.w));
    }
    #pragma unroll 2
    for (int i = s0; i < s1; ++i) {
        int s = perm_s[i];
        float4 xr, er;
        if (XF32) {
            xr = *(const float4*)(Xf + (size_t)s * DIM + l * 4);
        } else {
            ushort4 v = *(const ushort4*)(Xh + (size_t)s * DIM + l * 4);
            xr = make_float4(bf2f(v.x), bf2f(v.y), bf2f(v.z), bf2f(v.w));
        }
        if (EAPERM) {
            ushort4 v = *(const ushort4*)(EAh + (size_t)i * DIM + l * 4);
            er = make_float4(bf2f(v.x), bf2f(v.y), bf2f(v.z), bf2f(v.w));
        } else {
            int e = perm_e[i];
            er = *(const float4*)(EAf + (size_t)e * DIM + l * 4);
        }
        if (WEA) {
            ushort4 o;
            o.x = f2bf(er.x); o.y = f2bf(er.y); o.z = f2bf(er.z); o.w = f2bf(er.w);
            *(ushort4*)(EAout + (size_t)i * DIM + l * 4) = o;   // CSR slot order
        }
        acc.x += fmaxf(xr.x + er.x, 0.f);
        acc.y += fmaxf(xr.y + er.y, 0.f);
        acc.z += fmaxf(xr.z + er.z, 0.f);
        acc.w += fmaxf(xr.w + er.w, 0.f);
    }
    ushort4 o;
    o.x = f2bf(acc.x); o.y = f2bf(acc.y); o.z = f2bf(acc.z); o.w = f2bf(acc.w);
    *(ushort4*)(A16 + (size_t)wid * DIM + l * 4) = o;
}

// ---------------------------------------------------------------------------
// Weight convert+transpose via LDS 64x64 tiles (coalesced read AND write).
// out[Nc][K] bf16 = in[K][Nc] fp32. All 8 weights; 32 tiles each.
struct WPtrs {
    const float* w[8];
    ushort* o[8];
    int K[8];
    int Nc[8];
};
__global__ __launch_bounds__(256) void wconv_kernel(WPtrs p) {
    __shared__ float T[64][65];
    int w = blockIdx.x >> 5;                 // 8 weights x 32 tiles
    int tile = blockIdx.x & 31;
    int K = p.K[w], Nc = p.Nc[w];
    int tilesPerRow = Nc >> 6;               // tiles along Nc
    int tk = (tile / tilesPerRow) << 6;      // K origin
    int tc = (tile % tilesPerRow) << 6;      // Nc origin
    int tx = threadIdx.x & 63, ty = threadIdx.x >> 6;   // 64x4
    const float* in = p.w[w];
    #pragma unroll
    for (int r = 0; r < 16; ++r) {
        int kk = ty + r * 4;
        T[kk][tx] = in[(size_t)(tk + kk) * Nc + tc + tx];
    }
    __syncthreads();
    ushort* outp = p.o[w];
    #pragma unroll
    for (int r = 0; r < 16; ++r) {
        int cc = ty + r * 4;                 // output row = Nc index
        outp[(size_t)(tc + cc) * K + tk + tx] = f2bf(T[tx][cc]);
    }
}

// ---------------------------------------------------------------------------
// BN-fold for layers 2/3 (no ReLU): W2f[l][n][k] = bf16(sc[k]*W2T[n][k]),
// b2f[l][n] = b2[n] + sum_k (be[k]-mu[k]*sc[k])*W2T[n][k].
__global__ __launch_bounds__(64) void wfold_kernel(
        const ushort* __restrict__ WT2_2, const ushort* __restrict__ WT2_3,
        const float* __restrict__ stats,
        const float* __restrict__ g2, const float* __restrict__ be2,
        const float* __restrict__ g3, const float* __restrict__ be3,
        const float* __restrict__ b2_2, const float* __restrict__ b2_3,
        ushort* __restrict__ W2f, float* __restrict__ b2f) {
    const int l = blockIdx.x >> 8;          // layer sel (0->conv2, 1->conv3)
    const int n = blockIdx.x & 255;
    const int lane = threadIdx.x;
    const float invN = 1.0f / (float)NNODES;
    const ushort* WT = l ? WT2_3 : WT2_2;
    const float* gp = l ? g3 : g2;
    const float* bp = l ? be3 : be2;
    float part = 0.f;
    #pragma unroll
    for (int j = 0; j < 8; ++j) {
        int k = j * 64 + lane;
        int c = l * DIM2 + k;
        float mu = stats[c] * invN;
        float var = stats[1024 + c] * invN - mu * mu;
        float sc = gp[k] * rsqrtf(var + BN_EPS);
        float sh = bp[k] - mu * sc;
        float wv = bf2f(WT[(size_t)n * DIM2 + k]);
        W2f[(size_t)l * 131072 + (size_t)n * DIM2 + k] = f2bf(sc * wv);
        part += sh * wv;
    }
    #pragma unroll
    for (int o = 32; o > 0; o >>= 1) part += __shfl_down(part, o);
    if (lane == 0) b2f[l * 256 + n] = (l ? b2_3[n] : b2_2[n]) + part;
}

// ---------------------------------------------------------------------------
// MFMA GEMM: out[gr][gc] = sum_k A16[gr][k]*WT[gc][k] + bias[gc]
// Block 128x128, BK=64, 4 waves (2x2), 64x64/wave.
// Staging: global_load_lds width=16, both-sides XOR swizzle (rule #21).
template<int K, bool OUT_BF16, bool STATS, bool FINAL>
__global__ __launch_bounds__(256) void mfma_gemm(
        const ushort* __restrict__ A16, int lda,
        const ushort* __restrict__ WT,
        const float* __restrict__ bias, const float* __restrict__ bias2,
        float* __restrict__ Cf, ushort* __restrict__ C16, int ldc,
        float* __restrict__ stats, int Nc, int Mlimit,
        const float* __restrict__ meanP, const float* __restrict__ noiseP,
        float* __restrict__ zP, float* __restrict__ klP) {
    __shared__ ushort As[128 * 64];
    __shared__ ushort Bs[128 * 64];
    const int tid = threadIdx.x;
    const int lane = tid & 63;
    const int wv = tid >> 6, wr = wv >> 1, wc = wv & 1;
    const int l15 = lane & 15, lhi = lane >> 4;
    const int r0 = blockIdx.y * 128, c0 = blockIdx.x * 128;

    const int srow = lane >> 3;                       // 0..7
    const int scol = ((lane & 7) ^ srow) * 8;         // inverse-swizzled source col
    const int smask = (l15 & 7) << 4;                 // read-side swizzle mask

    f32x4 acc[4][4] = {};

    for (int k0 = 0; k0 < K; k0 += 64) {
        #pragma unroll
        for (int j = 0; j < 4; ++j) {
            const int jp = j * 4 + wv;
            const ushort* ga = A16 + (size_t)(r0 + jp * 8 + srow) * lda + k0 + scol;
            const ushort* gb = WT + (size_t)(c0 + jp * 8 + srow) * K + k0 + scol;
            __builtin_amdgcn_global_load_lds(
                (gconst_byte*)ga, (lds_byte*)((char*)As + jp * 1024), 16, 0, 0);
            __builtin_amdgcn_global_load_lds(
                (gconst_byte*)gb, (lds_byte*)((char*)Bs + jp * 1024), 16, 0, 0);
        }
        __syncthreads();
        #pragma unroll
        for (int kk = 0; kk < 2; ++kk) {
            bf16x8 a[4], b[4];
            #pragma unroll
            for (int m = 0; m < 4; ++m)
                a[m] = *(const bf16x8*)((const char*)As +
                        (wr * 64 + m * 16 + l15) * 128 + ((kk * 64 + lhi * 16) ^ smask));
            #pragma unroll
            for (int n = 0; n < 4; ++n)
                b[n] = *(const bf16x8*)((const char*)Bs +
                        (wc * 64 + n * 16 + l15) * 128 + ((kk * 64 + lhi * 16) ^ smask));
            #pragma unroll
            for (int m = 0; m < 4; ++m)
                #pragma unroll
                for (int n = 0; n < 4; ++n)
                    acc[m][n] = __builtin_amdgcn_mfma_f32_16x16x32_bf16(
                        a[m], b[n], acc[m][n], 0, 0, 0);
        }
        __syncthreads();
    }

    float bv[4];
    #pragma unroll
    for (int n = 0; n < 4; ++n) {
        int gc = c0 + wc * 64 + n * 16 + l15;
        bv[n] = (gc < DIM2) ? bias[gc] : bias2[gc - DIM2];
    }
    float sm[4] = {0.f, 0.f, 0.f, 0.f}, sq[4] = {0.f, 0.f, 0.f, 0.f};
    float kl = 0.f;
    #pragma unroll
    for (int m = 0; m < 4; ++m) {
        #pragma unroll
        for (int q = 0; q < 4; ++q) {
            int gr = r0 + wr * 64 + m * 16 + lhi * 4 + q;
            if (gr >= Mlimit) continue;
            #pragma unroll
            for (int n = 0; n < 4; ++n) {
                int gc = c0 + wc * 64 + n * 16 + l15;
                float v = acc[m][n][q] + bv[n];
                if (OUT_BF16) C16[(size_t)gr * ldc + gc] = f2bf(v);
                else          Cf[(size_t)gr * ldc + gc] = v;
                if (STATS) { sm[n] += v; sq[n] += v * v; }
                if (FINAL) {
                    size_t idx = (size_t)gr * DIM + gc;
                    float mean = meanP[idx];
                    float nz = noiseP[idx];
                    float e = expf(v);
                    zP[idx] = nz * e + mean;
                    kl += 1.f + 2.f * v - mean * mean - e * e;
                }
            }
        }
    }
    if (STATS) {
        #pragma unroll
        for (int n = 0; n < 4; ++n) {
            float sv = sm[n], qv = sq[n];
            sv += __shfl_xor(sv, 16); sv += __shfl_xor(sv, 32);
            qv += __shfl_xor(qv, 16); qv += __shfl_xor(qv, 32);
            if (lane < 16) {
                int gc = c0 + wc * 64 + n * 16 + l15;
                atomicAdd(&stats[gc], sv);
                atomicAdd(&stats[Nc + gc], qv);
            }
        }
    }
    if (FINAL) {
        #pragma unroll
        for (int o = 32; o > 0; o >>= 1) kl += __shfl_down(kl, o);
        if (lane == 0) {
            const float scale = 0.5f / ((float)NNODES * (float)NNODES);
            atomicAdd(klP, kl * scale);
        }
    }
}

// ---------------------------------------------------------------------------
// BN apply in-place on bf16 [NNODES, NCOLS] (layers 0/1, ReLU).
template<int NCOLS>
__global__ __launch_bounds__(256) void bn_apply_kernel(
        ushort* __restrict__ H16, const float* __restrict__ stats,
        const float* __restrict__ g0, const float* __restrict__ be0) {
    const float invN = 1.0f / (float)NNODES;
    const int n4 = NNODES * NCOLS / 4;
    for (int i = blockIdx.x * blockDim.x + threadIdx.x; i < n4;
         i += gridDim.x * blockDim.x) {
        int cbase = (i * 4) & (NCOLS - 1);
        ushort4 u = ((const ushort4*)H16)[i];
        float vv[4] = {bf2f(u.x), bf2f(u.y), bf2f(u.z), bf2f(u.w)};
        #pragma unroll
        for (int k = 0; k < 4; ++k) {
            int c = cbase + k;
            float mu = stats[c] * invN;
            float var = stats[NCOLS + c] * invN - mu * mu;
            float x = (vv[k] - mu) * rsqrtf(var + BN_EPS) * g0[c] + be0[c];
            vv[k] = fmaxf(x, 0.f);
        }
        ushort4 o;
        o.x = f2bf(vv[0]); o.y = f2bf(vv[1]); o.z = f2bf(vv[2]); o.w = f2bf(vv[3]);
        ((ushort4*)H16)[i] = o;
    }
}

// ---------------------------------------------------------------------------
extern "C" void kernel_launch(void* const* d_in, const int* in_sizes, int n_in,
                              void* d_out, int out_size, void* d_ws, size_t ws_size,
                              hipStream_t stream) {
    const float* x     = (const float*)d_in[0];
    const int*   ei    = (const int*)d_in[1];
    const float* ea    = (const float*)d_in[2];
    const float* noise = (const float*)d_in[3];
    const float *W1[4], *b1[4], *g[4], *be[4], *W2[4], *b2[4];
    for (int i = 0; i < 4; ++i) {
        W1[i] = (const float*)d_in[4 + 6 * i];
        b1[i] = (const float*)d_in[5 + 6 * i];
        g[i]  = (const float*)d_in[6 + 6 * i];
        be[i] = (const float*)d_in[7 + 6 * i];
        W2[i] = (const float*)d_in[8 + 6 * i];
        b2[i] = (const float*)d_in[9 + 6 * i];
    }
    float* out = (float*)d_out;
    float* klP = out + 3 * NDTOT;

    // --- workspace carve
    char* p = (char*)d_ws;
    auto carve = [&](size_t bytes) {
        char* r = p;
        p += (bytes + 255) & ~(size_t)255;
        return r;
    };
    ushort* Braw16 = (ushort*)carve((size_t)MPAD * 1024 * 2);   // GEMM1 out (<=1024 cols)
    ushort* H16    = (ushort*)carve((size_t)MPAD * DIM * 2);    // hidden bf16
    ushort* A16    = (ushort*)carve((size_t)MPAD * DIM * 2);    // agg out bf16
    ushort* WT16   = (ushort*)carve((size_t)8 * 131072 * 2);    // 8 transposed weights
    ushort* W2f    = (ushort*)carve((size_t)2 * 131072 * 2);    // folded L23 weights
    float*  b2f    = (float*)carve(512 * 4);                    // folded L23 biases
    float*  stats  = (float*)carve(4096 * 4 + NNODES * 4);      // stats + cnt (one memset)
    int*    cnt    = (int*)(stats + 4096);
    int*    off    = (int*)carve((NNODES + 8) * 4);
    int*    cur    = (int*)carve(NNODES * 4);
    int*    perm_e = (int*)carve(NEDGES * 4);
    int*    perm_s = (int*)carve(NEDGES * 4);
    size_t baseBytes = (size_t)(p - (char*)d_ws);
    ushort* ea16 = (ushort*)p;
    const bool useEa16 = (baseBytes + (size_t)NEDGES * DIM * 2) <= ws_size;

    const int edgeGrid = (NEDGES + 255) / 256;
    const int aggGrid = (NNODES * 64) / 256;

    // --- weight convert + transpose (once). o[2],o[3] adjacent -> merged L23 W1.
    WPtrs wp;
    for (int i = 0; i < 4; ++i) {
        wp.w[i] = W1[i];     wp.o[i] = WT16 + (size_t)i * 131072;
        wp.K[i] = DIM;       wp.Nc[i] = DIM2;
        wp.w[4 + i] = W2[i]; wp.o[4 + i] = WT16 + (size_t)(4 + i) * 131072;
        wp.K[4 + i] = DIM2;  wp.Nc[4 + i] = DIM;
    }
    hipLaunchKernelGGL(wconv_kernel, dim3(8 * 32), dim3(256), 0, stream, wp);

    // --- zero stats + cnt in one fill; build CSR (scan also zeroes KL)
    hipMemsetAsync(stats, 0, 4096 * 4 + NNODES * 4, stream);
    hipLaunchKernelGGL(hist_kernel, dim3(edgeGrid), dim3(256), 0, stream, ei, cnt);
    hipLaunchKernelGGL(scan_kernel, dim3(1), dim3(256), 0, stream, cnt, off, cur, klP);
    hipLaunchKernelGGL(scatter_kernel, dim3(edgeGrid), dim3(256), 0, stream,
                       ei, cur, perm_e, perm_s);

    dim3 blk(256);
    dim3 gemm1Grid(DIM2 / 128, MPAD / 128);     // (4,157)
    dim3 gemm1WGrid(1024 / 128, MPAD / 128);    // (8,157) merged L23
    dim3 gemm2Grid(DIM / 128, MPAD / 128);      // (2,157)
    const float* nf = nullptr;
    float* nfm = nullptr;

    // ---------------- layer 0 ----------------
    if (useEa16)
        hipLaunchKernelGGL((agg_kernel<true, false, true>), dim3(aggGrid), blk, 0, stream,
                           x, (const ushort*)nullptr, ea, (const ushort*)nullptr, ea16,
                           off, perm_e, perm_s, A16);
    else
        hipLaunchKernelGGL((agg_kernel<true, false, false>), dim3(aggGrid), blk, 0, stream,
                           x, (const ushort*)nullptr, ea, (const ushort*)nullptr, (ushort*)nullptr,
                           off, perm_e, perm_s, A16);
    hipLaunchKernelGGL((mfma_gemm<DIM, true, true, false>), gemm1Grid, blk, 0, stream,
                       A16, DIM, WT16, b1[0], b1[0],
                       nfm, Braw16, DIM2, stats, DIM2, NNODES, nf, nf, nfm, nfm);
    hipLaunchKernelGGL((bn_apply_kernel<DIM2>), dim3(2048), blk, 0, stream,
                       Braw16, stats, g[0], be[0]);
    hipLaunchKernelGGL((mfma_gemm<DIM2, true, false, false>), gemm2Grid, blk, 0, stream,
                       Braw16, DIM2, WT16 + 4 * 131072, b2[0], b2[0],
                       nfm, H16, DIM, nfm, DIM, NNODES, nf, nf, nfm, nfm);

    // ---------------- layer 1 ----------------
    if (useEa16)
        hipLaunchKernelGGL((agg_kernel<false, true, false>), dim3(aggGrid), blk, 0, stream,
                           (const float*)nullptr, H16, (const float*)nullptr, ea16, (ushort*)nullptr,
                           off, perm_e, perm_s, A16);
    else
        hipLaunchKernelGGL((agg_kernel<false, false, false>), dim3(aggGrid), blk, 0, stream,
                           (const float*)nullptr, H16, ea, (const ushort*)nullptr, (ushort*)nullptr,
                           off, perm_e, perm_s, A16);
    hipLaunchKernelGGL((mfma_gemm<DIM, true, true, false>), gemm1Grid, blk, 0, stream,
                       A16, DIM, WT16 + 1 * 131072, b1[1], b1[1],
                       nfm, Braw16, DIM2, stats + 1024, DIM2, NNODES, nf, nf, nfm, nfm);
    hipLaunchKernelGGL((bn_apply_kernel<DIM2>), dim3(2048), blk, 0, stream,
                       Braw16, stats + 1024, g[1], be[1]);
    hipLaunchKernelGGL((mfma_gemm<DIM2, true, false, false>), gemm2Grid, blk, 0, stream,
                       Braw16, DIM2, WT16 + 5 * 131072, b2[1], b2[1],
                       nfm, H16, DIM, nfm, DIM, NNODES, nf, nf, nfm, nfm);

    // ---------------- layers 2+3 (merged GEMM1; BN folded into GEMM2) --------
    if (useEa16)
        hipLaunchKernelGGL((agg_kernel<false, true, false>), dim3(aggGrid), blk, 0, stream,
                           (const float*)nullptr, H16, (const float*)nullptr, ea16, (ushort*)nullptr,
                           off, perm_e, perm_s, A16);
    else
        hipLaunchKernelGGL((agg_kernel<false, false, false>), dim3(aggGrid), blk, 0, stream,
                           (const float*)nullptr, H16, ea, (const ushort*)nullptr, (ushort*)nullptr,
                           off, perm_e, perm_s, A16);
    hipLaunchKernelGGL((mfma_gemm<DIM, true, true, false>), gemm1WGrid, blk, 0, stream,
                       A16, DIM, WT16 + 2 * 131072, b1[2], b1[3],
                       nfm, Braw16, 1024, stats + 2048, 1024, NNODES, nf, nf, nfm, nfm);
    hipLaunchKernelGGL(wfold_kernel, dim3(512), dim3(64), 0, stream,
                       WT16 + 6 * 131072, WT16 + 7 * 131072, stats + 2048,
                       g[2], be[2], g[3], be[3], b2[2], b2[3], W2f, b2f);
    // mean = Braw16[:,0:512] @ W2f_0 + b2f_0
    hipLaunchKernelGGL((mfma_gemm<DIM2, false, false, false>), gemm2Grid, blk, 0, stream,
                       Braw16, 1024, W2f, b2f, b2f,
                       out + NDTOT, (ushort*)nullptr, DIM, nfm, DIM, NNODES, nf, nf, nfm, nfm);
    // logstd = Braw16[:,512:1024] @ W2f_1 + b2f_1 ; fused z + KL
    hipLaunchKernelGGL((mfma_gemm<DIM2, false, false, true>), gemm2Grid, blk, 0, stream,
                       Braw16 + 512, 1024, W2f + 131072, b2f + 256, b2f + 256,
                       out + 2 * NDTOT, (ushort*)nullptr, DIM, nfm, DIM, NNODES,
                       out + NDTOT, noise, out, klP);
}